// Round 5
// baseline (268.423 us; speedup 1.0000x reference)
//
#include <hip/hip_runtime.h>
#include <hip/hip_bf16.h>
#include <cstddef>
#include <cstdint>

#define T_TOK 4096
#define H_DIM 2048
#define E_NUM 8
#define I_DIM 1024
#define TWO_I 2048
#define MROWS 6144      // worst-case 256-padded slot rows
#define MT_MAX 24       // MROWS/256
#define BK 64

typedef __attribute__((ext_vector_type(8))) short bf16x8;
typedef __attribute__((ext_vector_type(4))) float f32x4;
typedef __attribute__((ext_vector_type(4))) int   i32x4;

// -------- workspace layout (bytes); ws >= 128 MiB proven (round-2 fast path) --
#define WS_SCALE   0            // f32[4096]
#define WS_COUNTS  16384        // int[8]
#define WS_OFFP    16448        // int[9] (256-padded prefix)
#define WS_BUCKETS 16512        // int[8*4096]  ends 147584
#define WS_SLOTTOK 147584       // int[6144]    ends 172160
#define WS_XSG     (1u<<20)     // bf16[6144*2048] = 25.2 MB
#define WS_ACT     (28u<<20)    // bf16[6144*1024] = 12.6 MB
#define WS_WT      (42u<<20)    // shared w1t/w2t region, 67.1 MB -> ends ~109 MB

__device__ __forceinline__ short f2bf(float f) {
    uint32_t u = __builtin_bit_cast(uint32_t, f);
    u += 0x7fffu + ((u >> 16) & 1u);
    return (short)(u >> 16);
}

__device__ __forceinline__ void gload16(const void* g, void* l) {
    __builtin_amdgcn_global_load_lds(
        (const __attribute__((address_space(1))) void*)g,
        (__attribute__((address_space(3))) void*)l, 16, 0, 0);
}

// ---------------- router (vectorized float4, wave per token) ----------------
__global__ __launch_bounds__(256) void router_kernel(
    const float* __restrict__ x, const float* __restrict__ gw,
    float* __restrict__ scale, int* __restrict__ counts, int* __restrict__ buckets)
{
    const int wid  = threadIdx.x >> 6;
    const int lane = threadIdx.x & 63;
    const int t = blockIdx.x * 4 + wid;
    if (t >= T_TOK) return;

    float4 a4[E_NUM];
#pragma unroll
    for (int e = 0; e < E_NUM; ++e) a4[e] = make_float4(0.f, 0.f, 0.f, 0.f);

    const float4* xr  = (const float4*)(x + (size_t)t * H_DIM);
    const float4* gwv = (const float4*)gw;
#pragma unroll
    for (int it = 0; it < 8; ++it) {
        const int idx = lane + it * 64;        // float4 index, 512 per row
        float4 xv = xr[idx];
#pragma unroll
        for (int e = 0; e < E_NUM; ++e) {
            float4 wv = gwv[e * 512 + idx];
            a4[e].x = fmaf(xv.x, wv.x, a4[e].x);
            a4[e].y = fmaf(xv.y, wv.y, a4[e].y);
            a4[e].z = fmaf(xv.z, wv.z, a4[e].z);
            a4[e].w = fmaf(xv.w, wv.w, a4[e].w);
        }
    }
    float acc[E_NUM];
#pragma unroll
    for (int e = 0; e < E_NUM; ++e) {
        float v = (a4[e].x + a4[e].y) + (a4[e].z + a4[e].w);
#pragma unroll
        for (int off = 32; off > 0; off >>= 1) v += __shfl_xor(v, off);
        acc[e] = v;
    }
    if (lane == 0) {
        int best = 0; float bv = acc[0];
#pragma unroll
        for (int e = 1; e < E_NUM; ++e) { if (acc[e] > bv) { bv = acc[e]; best = e; } }
        scale[t] = 1.f / (1.f + expf(-bv));
        int pos = atomicAdd(&counts[best], 1);
        buckets[best * T_TOK + pos] = t;
    }
}

// ---------------- 256-padded prefix offsets ----------------
__global__ void offs_kernel(const int* __restrict__ counts, int* __restrict__ offP) {
    if (threadIdx.x == 0) {
        int run = 0;
#pragma unroll
        for (int e = 0; e < E_NUM; ++e) { offP[e] = run; run += (counts[e] + 255) & ~255; }
        offP[E_NUM] = run;
    }
}

// ---------------- gather: xsg[slot] = bf16(scale[tok] * x[tok]) ----------------
__global__ __launch_bounds__(256) void gather_kernel(
    const float* __restrict__ x, const float* __restrict__ scale,
    const int* __restrict__ counts, const int* __restrict__ offP,
    const int* __restrict__ buckets, short* __restrict__ xsg,
    int* __restrict__ slot_tok)
{
    const int r = blockIdx.x;          // slot row 0..6143
    int e = 0;
#pragma unroll
    for (int k = 1; k < E_NUM; ++k) if (r >= offP[k]) e = k;
    const int pos = r - offP[e];
    const bool valid = (r < offP[E_NUM]) && (pos < counts[e]);
    const int tok = valid ? buckets[e * T_TOK + pos] : -1;
    if (threadIdx.x == 0) slot_tok[r] = tok;

    short* orow = xsg + (size_t)r * H_DIM + threadIdx.x * 8;
    if (!valid) {
        i32x4 z = {0, 0, 0, 0};
        *(i32x4*)orow = z;
        return;
    }
    const float sc = scale[tok];
    const float* xr = x + (size_t)tok * H_DIM + threadIdx.x * 8;
    float4 a = *(const float4*)xr;
    float4 b = *(const float4*)(xr + 4);
    short o[8] __attribute__((aligned(16)));
    o[0] = f2bf(a.x * sc); o[1] = f2bf(a.y * sc);
    o[2] = f2bf(a.z * sc); o[3] = f2bf(a.w * sc);
    o[4] = f2bf(b.x * sc); o[5] = f2bf(b.y * sc);
    o[6] = f2bf(b.z * sc); o[7] = f2bf(b.w * sc);
    *(i32x4*)orow = *(const i32x4*)o;
}

// ---------------- weight transpose + bf16 convert ----------------
// src: [E][K][N] f32  ->  dst: [E][N][K] bf16
__global__ __launch_bounds__(256) void transpose_cvt_kernel(
    const float* __restrict__ src, short* __restrict__ dst, int K, int N)
{
    __shared__ float s[64][65];
    const int e  = blockIdx.z;
    const int k0 = blockIdx.x * 64;
    const int n0 = blockIdx.y * 64;
    const int t  = threadIdx.x;

    const float* S = src + ((size_t)e * K + k0) * N + n0;
    const int kr = t >> 4, nc = (t & 15) * 4;
#pragma unroll
    for (int i = 0; i < 4; ++i) {
        float4 v = *(const float4*)(S + (size_t)(kr + i * 16) * N + nc);
        s[kr + i * 16][nc + 0] = v.x;
        s[kr + i * 16][nc + 1] = v.y;
        s[kr + i * 16][nc + 2] = v.z;
        s[kr + i * 16][nc + 3] = v.w;
    }
    __syncthreads();

    const int nr = t >> 2, kc = (t & 3) * 16;
    short tmp[16] __attribute__((aligned(16)));
#pragma unroll
    for (int j = 0; j < 16; ++j) tmp[j] = f2bf(s[kc + j][nr]);
    short* D = dst + ((size_t)e * N + n0 + nr) * K + k0 + kc;
    *(i32x4*)D       = *(const i32x4*)tmp;
    *(i32x4*)(D + 8) = *(const i32x4*)(tmp + 8);
}

// ================== 8-phase 256x256x64 grouped MFMA GEMMs ==================
// 8 waves (2M x 4N), per-wave 128x64 out, per-phase quadrant 64x32 = 16 MFMA.
// LDS 128 KB: [2 dbuf][2 half][128 rows][64 k] bf16 for A and B.
// XOR swizzle: 16B-chunk c' = c ^ (row&7); staged via inverse-permuted global
// source (gload_lds writes linearly), read with same XOR.
// R5 change: ALL 4 stage-units of tile t+1 issued at TOP of iter t, before a
// counted vmcnt(8) that drains exactly tile t -> full-iteration issue-to-use
// distance (~900cy HBM latency covered), instead of last-unit-1-phase-before.

#define DO_PHASE(MQ, NQ, BAR_BEFORE_LOAD)                                      \
  {                                                                            \
    if (BAR_BEFORE_LOAD) __builtin_amdgcn_s_barrier();                         \
    bf16x8 af[4][2]; bf16x8 bg[2][2];                                          \
    _Pragma("unroll") for (int mf = 0; mf < 4; ++mf) {                         \
      _Pragma("unroll") for (int kf = 0; kf < 2; ++kf) {                       \
        af[mf][kf] = *(const bf16x8*)&sA[cbuf][wm * 8192 +                     \
            ((MQ) * 64 + mf * 16 + lm) * 64 + (((kf * 4 + lg) ^ lm7) << 3)];   \
      } }                                                                      \
    _Pragma("unroll") for (int nf = 0; nf < 2; ++nf) {                         \
      _Pragma("unroll") for (int kf = 0; kf < 2; ++kf) {                       \
        bg[nf][kf] = *(const bf16x8*)&sB[cbuf][bhB * 8192 +                    \
            (rbB + (NQ) * 32 + nf * 16) * 64 + (((kf * 4 + lg) ^ lm7) << 3)];  \
      } }                                                                      \
    if (!(BAR_BEFORE_LOAD)) __builtin_amdgcn_s_barrier();                      \
    __builtin_amdgcn_s_setprio(1);                                             \
    _Pragma("unroll") for (int mf = 0; mf < 4; ++mf)                           \
      _Pragma("unroll") for (int nf = 0; nf < 2; ++nf)                         \
        _Pragma("unroll") for (int kf = 0; kf < 2; ++kf)                       \
          acc[(MQ) * 4 + mf][(NQ) * 2 + nf] =                                  \
              __builtin_amdgcn_mfma_f32_16x16x32_bf16(af[mf][kf], bg[nf][kf],  \
                  acc[(MQ) * 4 + mf][(NQ) * 2 + nf], 0, 0, 0);                 \
    __builtin_amdgcn_s_setprio(0);                                             \
    __builtin_amdgcn_s_barrier();                                              \
  }

__global__ __launch_bounds__(512) void gemm1_8ph_kernel(
    const short* __restrict__ xsg, const short* __restrict__ w1t,
    const int* __restrict__ offP, short* __restrict__ act)
{
    __shared__ short sA[2][16384];   // [dbuf][half*8192 + row*64 + k]
    __shared__ short sB[2][16384];

    const int bid = blockIdx.x;                      // 192 = 8 * 24
    const int wg  = (bid & 7) * MT_MAX + (bid >> 3); // bijective XCD swizzle
    const int nt  = wg / MT_MAX;                     // 0..7  (B panel; same XCD)
    const int mt  = wg % MT_MAX;
    const int m0  = mt << 8;
    if (m0 >= offP[E_NUM]) return;
    const int f0  = nt << 7;                         // 128 f-cols per tile

    int e = 0;
#pragma unroll
    for (int k = 1; k < E_NUM; ++k) if (m0 >= offP[k]) e = k;

    const int tid = threadIdx.x, lane = tid & 63, w = tid >> 6;
    const int wm = w >> 2, wn = w & 3;
    const int lm = lane & 15, lg = lane >> 4, lm7 = lane & 7;
    const int bhB = wn >> 1;
    const int rbB = (wn & 1) * 64 + lm;

    // staging geometry: wave w, call i in {0,1}, lane L:
    //   LDS row rw = w*16 + i*8 + (L>>3); data chunk c = (L&7) ^ (L>>3)
    const int rw0   = w * 16 + (lane >> 3);
    const int cperm = ((lane & 7) ^ (lane >> 3)) * 8;   // shorts

    const short* srcA00 = xsg + (size_t)(m0 +   0 + rw0    ) * H_DIM + cperm;
    const short* srcA01 = xsg + (size_t)(m0 +   0 + rw0 + 8) * H_DIM + cperm;
    const short* srcA10 = xsg + (size_t)(m0 + 128 + rw0    ) * H_DIM + cperm;
    const short* srcA11 = xsg + (size_t)(m0 + 128 + rw0 + 8) * H_DIM + cperm;

    // B rows interleave up/gate in 16-col chunks: LDS n-row nn = half*128+rb
    //   w1t row = ((rb>>4)&1)*I + f0 + (half*4 + (rb>>5))*16 + (rb&15)
    auto brow = [&](int half, int rb) -> const short* {
        int grow = ((rb >> 4) & 1) * I_DIM + f0 + (half * 4 + (rb >> 5)) * 16 + (rb & 15);
        return w1t + ((size_t)e * TWO_I + grow) * H_DIM + cperm;
    };
    const short* srcB00 = brow(0, rw0);
    const short* srcB01 = brow(0, rw0 + 8);
    const short* srcB10 = brow(1, rw0);
    const short* srcB11 = brow(1, rw0 + 8);

    auto stage_tile = [&](int tbuf, int kb) {
        gload16(srcA00 + kb, &sA[tbuf][(w * 2    ) * 512]);
        gload16(srcA01 + kb, &sA[tbuf][(w * 2 + 1) * 512]);
        gload16(srcA10 + kb, &sA[tbuf][8192 + (w * 2    ) * 512]);
        gload16(srcA11 + kb, &sA[tbuf][8192 + (w * 2 + 1) * 512]);
        gload16(srcB00 + kb, &sB[tbuf][(w * 2    ) * 512]);
        gload16(srcB01 + kb, &sB[tbuf][(w * 2 + 1) * 512]);
        gload16(srcB10 + kb, &sB[tbuf][8192 + (w * 2    ) * 512]);
        gload16(srcB11 + kb, &sB[tbuf][8192 + (w * 2 + 1) * 512]);
    };

    f32x4 acc[8][4];
#pragma unroll
    for (int i = 0; i < 8; ++i)
#pragma unroll
        for (int j = 0; j < 4; ++j) acc[i][j] = (f32x4){0.f, 0.f, 0.f, 0.f};

    stage_tile(0, 0);
    int cbuf = 0;
    const int NKT = H_DIM / BK;    // 32
#pragma unroll 2
    for (int t = 0; t < NKT; ++t) {
        if (t + 1 < NKT) {
            stage_tile(cbuf ^ 1, (t + 1) * BK);          // full tile t+1 in flight
            asm volatile("s_waitcnt vmcnt(8)" ::: "memory");  // drain tile t only
        } else {
            asm volatile("s_waitcnt vmcnt(0)" ::: "memory");
        }
        DO_PHASE(0, 0, true);
        DO_PHASE(0, 1, false);
        DO_PHASE(1, 0, false);
        DO_PHASE(1, 1, false);
        cbuf ^= 1;
    }

    // epilogue: act = up * gate * sigmoid(gate)
#pragma unroll
    for (int a = 0; a < 8; ++a) {
        const int mrow = m0 + wm * 128 + (a >> 2) * 64 + (a & 3) * 16 + lg * 4;
#pragma unroll
        for (int q = 0; q < 2; ++q) {
            const int fcol = f0 + (wn * 2 + q) * 16 + lm;
#pragma unroll
            for (int r = 0; r < 4; ++r) {
                float up = acc[a][q * 2][r];
                float gt = acc[a][q * 2 + 1][r];
                float v  = up * gt / (1.f + expf(-gt));
                act[(size_t)(mrow + r) * I_DIM + fcol] = f2bf(v);
            }
        }
    }
}

__global__ __launch_bounds__(512) void gemm2_8ph_kernel(
    const short* __restrict__ actm, const short* __restrict__ w2t,
    const int* __restrict__ offP, const int* __restrict__ slot_tok,
    float* __restrict__ out)
{
    __shared__ short sA[2][16384];
    __shared__ short sB[2][16384];

    const int bid = blockIdx.x;
    const int wg  = (bid & 7) * MT_MAX + (bid >> 3);
    const int nt  = wg / MT_MAX;
    const int mt  = wg % MT_MAX;
    const int m0  = mt << 8;
    if (m0 >= offP[E_NUM]) return;
    const int h0  = nt << 8;                         // 256 h-cols per tile

    int e = 0;
#pragma unroll
    for (int k = 1; k < E_NUM; ++k) if (m0 >= offP[k]) e = k;

    const int tid = threadIdx.x, lane = tid & 63, w = tid >> 6;
    const int wm = w >> 2, wn = w & 3;
    const int lm = lane & 15, lg = lane >> 4, lm7 = lane & 7;
    const int bhB = wn >> 1;
    const int rbB = (wn & 1) * 64 + lm;

    const int rw0   = w * 16 + (lane >> 3);
    const int cperm = ((lane & 7) ^ (lane >> 3)) * 8;

    const short* srcA00 = actm + (size_t)(m0 +   0 + rw0    ) * I_DIM + cperm;
    const short* srcA01 = actm + (size_t)(m0 +   0 + rw0 + 8) * I_DIM + cperm;
    const short* srcA10 = actm + (size_t)(m0 + 128 + rw0    ) * I_DIM + cperm;
    const short* srcA11 = actm + (size_t)(m0 + 128 + rw0 + 8) * I_DIM + cperm;

    const short* srcB00 = w2t + ((size_t)e * H_DIM + h0 +   0 + rw0    ) * I_DIM + cperm;
    const short* srcB01 = w2t + ((size_t)e * H_DIM + h0 +   0 + rw0 + 8) * I_DIM + cperm;
    const short* srcB10 = w2t + ((size_t)e * H_DIM + h0 + 128 + rw0    ) * I_DIM + cperm;
    const short* srcB11 = w2t + ((size_t)e * H_DIM + h0 + 128 + rw0 + 8) * I_DIM + cperm;

    auto stage_tile = [&](int tbuf, int kb) {
        gload16(srcA00 + kb, &sA[tbuf][(w * 2    ) * 512]);
        gload16(srcA01 + kb, &sA[tbuf][(w * 2 + 1) * 512]);
        gload16(srcA10 + kb, &sA[tbuf][8192 + (w * 2    ) * 512]);
        gload16(srcA11 + kb, &sA[tbuf][8192 + (w * 2 + 1) * 512]);
        gload16(srcB00 + kb, &sB[tbuf][(w * 2    ) * 512]);
        gload16(srcB01 + kb, &sB[tbuf][(w * 2 + 1) * 512]);
        gload16(srcB10 + kb, &sB[tbuf][8192 + (w * 2    ) * 512]);
        gload16(srcB11 + kb, &sB[tbuf][8192 + (w * 2 + 1) * 512]);
    };

    f32x4 acc[8][4];
#pragma unroll
    for (int i = 0; i < 8; ++i)
#pragma unroll
        for (int j = 0; j < 4; ++j) acc[i][j] = (f32x4){0.f, 0.f, 0.f, 0.f};

    stage_tile(0, 0);
    int cbuf = 0;
    const int NKT = I_DIM / BK;    // 16
#pragma unroll 2
    for (int t = 0; t < NKT; ++t) {
        if (t + 1 < NKT) {
            stage_tile(cbuf ^ 1, (t + 1) * BK);
            asm volatile("s_waitcnt vmcnt(8)" ::: "memory");
        } else {
            asm volatile("s_waitcnt vmcnt(0)" ::: "memory");
        }
        DO_PHASE(0, 0, true);
        DO_PHASE(0, 1, false);
        DO_PHASE(1, 0, false);
        DO_PHASE(1, 1, false);
        cbuf ^= 1;
    }

    // epilogue: scatter rows to out via slot_tok
#pragma unroll
    for (int a = 0; a < 8; ++a) {
        const int mloc = wm * 128 + (a >> 2) * 64 + (a & 3) * 16 + lg * 4;
#pragma unroll
        for (int r = 0; r < 4; ++r) {
            const int tok = slot_tok[m0 + mloc + r];
            if (tok < 0) continue;
            float* orow = out + (size_t)tok * H_DIM + h0;
#pragma unroll
            for (int b = 0; b < 4; ++b) {
                const int hcol = wn * 64 + (b >> 1) * 32 + (b & 1) * 16 + lm;
                orow[hcol] = acc[a][b][r];
            }
        }
    }
}

extern "C" void kernel_launch(void* const* d_in, const int* in_sizes, int n_in,
                              void* d_out, int out_size, void* d_ws, size_t ws_size,
                              hipStream_t stream) {
    const float* x   = (const float*)d_in[0];
    const float* gw  = (const float*)d_in[1];
    const float* gup = (const float*)d_in[2];
    const float* dw  = (const float*)d_in[3];
    float* out = (float*)d_out;

    char* ws = (char*)d_ws;
    float* scale    = (float*)(ws + WS_SCALE);
    int*   counts   = (int*)(ws + WS_COUNTS);
    int*   offP     = (int*)(ws + WS_OFFP);
    int*   buckets  = (int*)(ws + WS_BUCKETS);
    int*   slot_tok = (int*)(ws + WS_SLOTTOK);
    short* xsg      = (short*)(ws + WS_XSG);
    short* act      = (short*)(ws + WS_ACT);
    short* wt       = (short*)(ws + WS_WT);    // shared: w1t then w2t

    hipMemsetAsync(counts, 0, E_NUM * sizeof(int), stream);
    router_kernel<<<T_TOK / 4, 256, 0, stream>>>(x, gw, scale, counts, buckets);
    offs_kernel<<<1, 64, 0, stream>>>(counts, offP);
    gather_kernel<<<MROWS, 256, 0, stream>>>(x, scale, counts, offP, buckets, xsg, slot_tok);

    // w1t = transpose(gate_up_weight) bf16, then GEMM1 (+SwiGLU)
    dim3 gt1(H_DIM / 64, TWO_I / 64, E_NUM);
    transpose_cvt_kernel<<<gt1, 256, 0, stream>>>(gup, wt, H_DIM, TWO_I);
    gemm1_8ph_kernel<<<8 * MT_MAX, 512, 0, stream>>>(xsg, wt, offP, act);

    // w2t = transpose(down_weight) bf16 (reuses region), then GEMM2 (+scatter)
    dim3 gt2(I_DIM / 64, H_DIM / 64, E_NUM);
    transpose_cvt_kernel<<<gt2, 256, 0, stream>>>(dw, wt, I_DIM, H_DIM);
    gemm2_8ph_kernel<<<8 * MT_MAX, 512, 0, stream>>>(act, wt, offP, slot_tok, out);
}

// Round 6
// 243.245 us; speedup vs baseline: 1.1035x; 1.1035x over previous
//
#include <hip/hip_runtime.h>
#include <hip/hip_bf16.h>
#include <cstddef>
#include <cstdint>

#define T_TOK 4096
#define H_DIM 2048
#define E_NUM 8
#define I_DIM 1024
#define TWO_I 2048
#define MROWS 6144      // worst-case 256-padded slot rows
#define MT_MAX 24       // MROWS/256
#define BK 64

typedef __attribute__((ext_vector_type(8))) short bf16x8;
typedef __attribute__((ext_vector_type(4))) float f32x4;
typedef __attribute__((ext_vector_type(4))) int   i32x4;

// -------- workspace layout (bytes); ws >= 128 MiB proven (round-2 fast path) --
#define WS_SCALE   0            // f32[4096]
#define WS_COUNTS  16384        // int[8]
#define WS_OFFP    16448        // int[9] (256-padded prefix)
#define WS_BUCKETS 16512        // int[8*4096]  ends 147584
#define WS_SLOTTOK 147584       // int[6144]    ends 172160
#define WS_XSG     (1u<<20)     // bf16[6144*2048] = 25.2 MB
#define WS_ACT     (28u<<20)    // bf16[6144*1024] = 12.6 MB
#define WS_WT      (42u<<20)    // shared w1t/w2t region, 67.1 MB -> ends ~109 MB

__device__ __forceinline__ short f2bf(float f) {
    uint32_t u = __builtin_bit_cast(uint32_t, f);
    u += 0x7fffu + ((u >> 16) & 1u);
    return (short)(u >> 16);
}

__device__ __forceinline__ void gload16(const void* g, void* l) {
    __builtin_amdgcn_global_load_lds(
        (const __attribute__((address_space(1))) void*)g,
        (__attribute__((address_space(3))) void*)l, 16, 0, 0);
}

// ---------------- router (vectorized float4, wave per token) ----------------
__global__ __launch_bounds__(256) void router_kernel(
    const float* __restrict__ x, const float* __restrict__ gw,
    float* __restrict__ scale, int* __restrict__ counts, int* __restrict__ buckets)
{
    const int wid  = threadIdx.x >> 6;
    const int lane = threadIdx.x & 63;
    const int t = blockIdx.x * 4 + wid;
    if (t >= T_TOK) return;

    float4 a4[E_NUM];
#pragma unroll
    for (int e = 0; e < E_NUM; ++e) a4[e] = make_float4(0.f, 0.f, 0.f, 0.f);

    const float4* xr  = (const float4*)(x + (size_t)t * H_DIM);
    const float4* gwv = (const float4*)gw;
#pragma unroll
    for (int it = 0; it < 8; ++it) {
        const int idx = lane + it * 64;        // float4 index, 512 per row
        float4 xv = xr[idx];
#pragma unroll
        for (int e = 0; e < E_NUM; ++e) {
            float4 wv = gwv[e * 512 + idx];
            a4[e].x = fmaf(xv.x, wv.x, a4[e].x);
            a4[e].y = fmaf(xv.y, wv.y, a4[e].y);
            a4[e].z = fmaf(xv.z, wv.z, a4[e].z);
            a4[e].w = fmaf(xv.w, wv.w, a4[e].w);
        }
    }
    float acc[E_NUM];
#pragma unroll
    for (int e = 0; e < E_NUM; ++e) {
        float v = (a4[e].x + a4[e].y) + (a4[e].z + a4[e].w);
#pragma unroll
        for (int off = 32; off > 0; off >>= 1) v += __shfl_xor(v, off);
        acc[e] = v;
    }
    if (lane == 0) {
        int best = 0; float bv = acc[0];
#pragma unroll
        for (int e = 1; e < E_NUM; ++e) { if (acc[e] > bv) { bv = acc[e]; best = e; } }
        scale[t] = 1.f / (1.f + expf(-bv));
        int pos = atomicAdd(&counts[best], 1);
        buckets[best * T_TOK + pos] = t;
    }
}

// ---------------- 256-padded prefix offsets ----------------
__global__ void offs_kernel(const int* __restrict__ counts, int* __restrict__ offP) {
    if (threadIdx.x == 0) {
        int run = 0;
#pragma unroll
        for (int e = 0; e < E_NUM; ++e) { offP[e] = run; run += (counts[e] + 255) & ~255; }
        offP[E_NUM] = run;
    }
}

// ---------------- gather: xsg[slot] = bf16(scale[tok] * x[tok]) ----------------
__global__ __launch_bounds__(256) void gather_kernel(
    const float* __restrict__ x, const float* __restrict__ scale,
    const int* __restrict__ counts, const int* __restrict__ offP,
    const int* __restrict__ buckets, short* __restrict__ xsg,
    int* __restrict__ slot_tok)
{
    const int r = blockIdx.x;          // slot row 0..6143
    int e = 0;
#pragma unroll
    for (int k = 1; k < E_NUM; ++k) if (r >= offP[k]) e = k;
    const int pos = r - offP[e];
    const bool valid = (r < offP[E_NUM]) && (pos < counts[e]);
    const int tok = valid ? buckets[e * T_TOK + pos] : -1;
    if (threadIdx.x == 0) slot_tok[r] = tok;

    short* orow = xsg + (size_t)r * H_DIM + threadIdx.x * 8;
    if (!valid) {
        i32x4 z = {0, 0, 0, 0};
        *(i32x4*)orow = z;
        return;
    }
    const float sc = scale[tok];
    const float* xr = x + (size_t)tok * H_DIM + threadIdx.x * 8;
    float4 a = *(const float4*)xr;
    float4 b = *(const float4*)(xr + 4);
    short o[8] __attribute__((aligned(16)));
    o[0] = f2bf(a.x * sc); o[1] = f2bf(a.y * sc);
    o[2] = f2bf(a.z * sc); o[3] = f2bf(a.w * sc);
    o[4] = f2bf(b.x * sc); o[5] = f2bf(b.y * sc);
    o[6] = f2bf(b.z * sc); o[7] = f2bf(b.w * sc);
    *(i32x4*)orow = *(const i32x4*)o;
}

// ---------------- weight transpose + bf16 convert ----------------
// src: [E][K][N] f32  ->  dst: [E][N][K] bf16
__global__ __launch_bounds__(256) void transpose_cvt_kernel(
    const float* __restrict__ src, short* __restrict__ dst, int K, int N)
{
    __shared__ float s[64][65];
    const int e  = blockIdx.z;
    const int k0 = blockIdx.x * 64;
    const int n0 = blockIdx.y * 64;
    const int t  = threadIdx.x;

    const float* S = src + ((size_t)e * K + k0) * N + n0;
    const int kr = t >> 4, nc = (t & 15) * 4;
#pragma unroll
    for (int i = 0; i < 4; ++i) {
        float4 v = *(const float4*)(S + (size_t)(kr + i * 16) * N + nc);
        s[kr + i * 16][nc + 0] = v.x;
        s[kr + i * 16][nc + 1] = v.y;
        s[kr + i * 16][nc + 2] = v.z;
        s[kr + i * 16][nc + 3] = v.w;
    }
    __syncthreads();

    const int nr = t >> 2, kc = (t & 3) * 16;
    short tmp[16] __attribute__((aligned(16)));
#pragma unroll
    for (int j = 0; j < 16; ++j) tmp[j] = f2bf(s[kc + j][nr]);
    short* D = dst + ((size_t)e * N + n0 + nr) * K + k0 + kc;
    *(i32x4*)D       = *(const i32x4*)tmp;
    *(i32x4*)(D + 8) = *(const i32x4*)(tmp + 8);
}

// ================== 256x256x64 grouped MFMA GEMMs ==================
// 8 waves (2M x 4N), per-wave 128x64 out. LDS 128 KB dbuf.
// XOR swizzle (bank-conflict-free, verified 0 conflicts): 16B-chunk
// c' = c ^ (row&7), staged via inverse-permuted global source.
// R6: ONE barrier-pair per K-tile; 24 ds_read_b128/wave/iter with operand
// reuse (af held across NQ, bg0/bg1 held across MQ); counted vmcnt(8).

#define LDAFRAG(MQ, mf, kf) (*(const bf16x8*)&sA[cbuf][wm * 8192 +            \
    ((MQ) * 64 + (mf) * 16 + lm) * 64 + ((((kf) * 4 + lg) ^ lm7) << 3)])
#define LDBFRAG(NQ, nf, kf) (*(const bf16x8*)&sB[cbuf][bhB * 8192 +           \
    (rbB + (NQ) * 32 + (nf) * 16) * 64 + ((((kf) * 4 + lg) ^ lm7) << 3)])

#define MFMA_QUAD(MQ, NQ, AARR, BARR)                                          \
    __builtin_amdgcn_s_setprio(1);                                             \
    _Pragma("unroll") for (int mf = 0; mf < 4; ++mf)                           \
      _Pragma("unroll") for (int nf = 0; nf < 2; ++nf)                         \
        _Pragma("unroll") for (int kf = 0; kf < 2; ++kf)                       \
          acc[(MQ) * 4 + mf][(NQ) * 2 + nf] =                                  \
              __builtin_amdgcn_mfma_f32_16x16x32_bf16(AARR[mf][kf],            \
                  BARR[nf][kf], acc[(MQ) * 4 + mf][(NQ) * 2 + nf], 0, 0, 0);   \
    __builtin_amdgcn_s_setprio(0);

#define COMPUTE_TILE()                                                         \
  {                                                                            \
    __builtin_amdgcn_sched_barrier(0);                                         \
    bf16x8 af[4][2], bg0[2][2], bg1[2][2];                                     \
    _Pragma("unroll") for (int mf = 0; mf < 4; ++mf)                           \
      _Pragma("unroll") for (int kf = 0; kf < 2; ++kf)                         \
        af[mf][kf] = LDAFRAG(0, mf, kf);                                       \
    _Pragma("unroll") for (int nf = 0; nf < 2; ++nf)                           \
      _Pragma("unroll") for (int kf = 0; kf < 2; ++kf)                         \
        bg0[nf][kf] = LDBFRAG(0, nf, kf);                                      \
    MFMA_QUAD(0, 0, af, bg0)                                                   \
    _Pragma("unroll") for (int nf = 0; nf < 2; ++nf)                           \
      _Pragma("unroll") for (int kf = 0; kf < 2; ++kf)                         \
        bg1[nf][kf] = LDBFRAG(1, nf, kf);                                      \
    MFMA_QUAD(0, 1, af, bg1)                                                   \
    _Pragma("unroll") for (int mf = 0; mf < 4; ++mf)                           \
      _Pragma("unroll") for (int kf = 0; kf < 2; ++kf)                         \
        af[mf][kf] = LDAFRAG(1, mf, kf);                                       \
    MFMA_QUAD(1, 1, af, bg1)                                                   \
    MFMA_QUAD(1, 0, af, bg0)                                                   \
    __builtin_amdgcn_sched_barrier(0);                                         \
  }

__global__ __launch_bounds__(512) void gemm1_8ph_kernel(
    const short* __restrict__ xsg, const short* __restrict__ w1t,
    const int* __restrict__ offP, short* __restrict__ act)
{
    __shared__ short sA[2][16384];   // [dbuf][half*8192 + row*64 + k]
    __shared__ short sB[2][16384];

    const int bid = blockIdx.x;                      // 192 = 8 * 24
    const int wg  = (bid & 7) * MT_MAX + (bid >> 3); // bijective XCD swizzle
    const int nt  = wg / MT_MAX;                     // 0..7  (B panel; same XCD)
    const int mt  = wg % MT_MAX;
    const int m0  = mt << 8;
    if (m0 >= offP[E_NUM]) return;
    const int f0  = nt << 7;                         // 128 f-cols per tile

    int e = 0;
#pragma unroll
    for (int k = 1; k < E_NUM; ++k) if (m0 >= offP[k]) e = k;

    const int tid = threadIdx.x, lane = tid & 63, w = tid >> 6;
    const int wm = w >> 2, wn = w & 3;
    const int lm = lane & 15, lg = lane >> 4, lm7 = lane & 7;
    const int bhB = wn >> 1;
    const int rbB = (wn & 1) * 64 + lm;

    // staging geometry: wave w, call i in {0,1}, lane L:
    //   LDS row rw = w*16 + i*8 + (L>>3); data chunk c = (L&7) ^ (L>>3)
    const int rw0   = w * 16 + (lane >> 3);
    const int cperm = ((lane & 7) ^ (lane >> 3)) * 8;   // shorts

    const short* srcA00 = xsg + (size_t)(m0 +   0 + rw0    ) * H_DIM + cperm;
    const short* srcA01 = xsg + (size_t)(m0 +   0 + rw0 + 8) * H_DIM + cperm;
    const short* srcA10 = xsg + (size_t)(m0 + 128 + rw0    ) * H_DIM + cperm;
    const short* srcA11 = xsg + (size_t)(m0 + 128 + rw0 + 8) * H_DIM + cperm;

    // B rows interleave up/gate in 16-col chunks: LDS n-row nn = half*128+rb
    //   w1t row = ((rb>>4)&1)*I + f0 + (half*4 + (rb>>5))*16 + (rb&15)
    auto brow = [&](int half, int rb) -> const short* {
        int grow = ((rb >> 4) & 1) * I_DIM + f0 + (half * 4 + (rb >> 5)) * 16 + (rb & 15);
        return w1t + ((size_t)e * TWO_I + grow) * H_DIM + cperm;
    };
    const short* srcB00 = brow(0, rw0);
    const short* srcB01 = brow(0, rw0 + 8);
    const short* srcB10 = brow(1, rw0);
    const short* srcB11 = brow(1, rw0 + 8);

    auto stage_tile = [&](int tbuf, int kb) {
        gload16(srcA00 + kb, &sA[tbuf][(w * 2    ) * 512]);
        gload16(srcA01 + kb, &sA[tbuf][(w * 2 + 1) * 512]);
        gload16(srcA10 + kb, &sA[tbuf][8192 + (w * 2    ) * 512]);
        gload16(srcA11 + kb, &sA[tbuf][8192 + (w * 2 + 1) * 512]);
        gload16(srcB00 + kb, &sB[tbuf][(w * 2    ) * 512]);
        gload16(srcB01 + kb, &sB[tbuf][(w * 2 + 1) * 512]);
        gload16(srcB10 + kb, &sB[tbuf][8192 + (w * 2    ) * 512]);
        gload16(srcB11 + kb, &sB[tbuf][8192 + (w * 2 + 1) * 512]);
    };

    f32x4 acc[8][4];
#pragma unroll
    for (int i = 0; i < 8; ++i)
#pragma unroll
        for (int j = 0; j < 4; ++j) acc[i][j] = (f32x4){0.f, 0.f, 0.f, 0.f};

    stage_tile(0, 0);
    int cbuf = 0;
    const int NKT = H_DIM / BK;    // 32
#pragma unroll 2
    for (int t = 0; t < NKT; ++t) {
        if (t + 1 < NKT) {
            stage_tile(cbuf ^ 1, (t + 1) * BK);          // full tile t+1 in flight
            asm volatile("s_waitcnt vmcnt(8)" ::: "memory");  // drain tile t only
        } else {
            asm volatile("s_waitcnt vmcnt(0)" ::: "memory");
        }
        __builtin_amdgcn_s_barrier();     // all waves' tile-t loads complete
        COMPUTE_TILE();
        __builtin_amdgcn_s_barrier();     // all waves done reading cbuf
        cbuf ^= 1;
    }

    // epilogue: act = up * gate * sigmoid(gate)
#pragma unroll
    for (int a = 0; a < 8; ++a) {
        const int mrow = m0 + wm * 128 + (a >> 2) * 64 + (a & 3) * 16 + lg * 4;
#pragma unroll
        for (int q = 0; q < 2; ++q) {
            const int fcol = f0 + (wn * 2 + q) * 16 + lm;
#pragma unroll
            for (int r = 0; r < 4; ++r) {
                float up = acc[a][q * 2][r];
                float gt = acc[a][q * 2 + 1][r];
                float v  = up * gt / (1.f + expf(-gt));
                act[(size_t)(mrow + r) * I_DIM + fcol] = f2bf(v);
            }
        }
    }
}

__global__ __launch_bounds__(512) void gemm2_8ph_kernel(
    const short* __restrict__ actm, const short* __restrict__ w2t,
    const int* __restrict__ offP, const int* __restrict__ slot_tok,
    float* __restrict__ out)
{
    __shared__ short sA[2][16384];
    __shared__ short sB[2][16384];

    const int bid = blockIdx.x;
    const int wg  = (bid & 7) * MT_MAX + (bid >> 3);
    const int nt  = wg / MT_MAX;
    const int mt  = wg % MT_MAX;
    const int m0  = mt << 8;
    if (m0 >= offP[E_NUM]) return;
    const int h0  = nt << 8;                         // 256 h-cols per tile

    int e = 0;
#pragma unroll
    for (int k = 1; k < E_NUM; ++k) if (m0 >= offP[k]) e = k;

    const int tid = threadIdx.x, lane = tid & 63, w = tid >> 6;
    const int wm = w >> 2, wn = w & 3;
    const int lm = lane & 15, lg = lane >> 4, lm7 = lane & 7;
    const int bhB = wn >> 1;
    const int rbB = (wn & 1) * 64 + lm;

    const int rw0   = w * 16 + (lane >> 3);
    const int cperm = ((lane & 7) ^ (lane >> 3)) * 8;

    const short* srcA00 = actm + (size_t)(m0 +   0 + rw0    ) * I_DIM + cperm;
    const short* srcA01 = actm + (size_t)(m0 +   0 + rw0 + 8) * I_DIM + cperm;
    const short* srcA10 = actm + (size_t)(m0 + 128 + rw0    ) * I_DIM + cperm;
    const short* srcA11 = actm + (size_t)(m0 + 128 + rw0 + 8) * I_DIM + cperm;

    const short* srcB00 = w2t + ((size_t)e * H_DIM + h0 +   0 + rw0    ) * I_DIM + cperm;
    const short* srcB01 = w2t + ((size_t)e * H_DIM + h0 +   0 + rw0 + 8) * I_DIM + cperm;
    const short* srcB10 = w2t + ((size_t)e * H_DIM + h0 + 128 + rw0    ) * I_DIM + cperm;
    const short* srcB11 = w2t + ((size_t)e * H_DIM + h0 + 128 + rw0 + 8) * I_DIM + cperm;

    auto stage_tile = [&](int tbuf, int kb) {
        gload16(srcA00 + kb, &sA[tbuf][(w * 2    ) * 512]);
        gload16(srcA01 + kb, &sA[tbuf][(w * 2 + 1) * 512]);
        gload16(srcA10 + kb, &sA[tbuf][8192 + (w * 2    ) * 512]);
        gload16(srcA11 + kb, &sA[tbuf][8192 + (w * 2 + 1) * 512]);
        gload16(srcB00 + kb, &sB[tbuf][(w * 2    ) * 512]);
        gload16(srcB01 + kb, &sB[tbuf][(w * 2 + 1) * 512]);
        gload16(srcB10 + kb, &sB[tbuf][8192 + (w * 2    ) * 512]);
        gload16(srcB11 + kb, &sB[tbuf][8192 + (w * 2 + 1) * 512]);
    };

    f32x4 acc[8][4];
#pragma unroll
    for (int i = 0; i < 8; ++i)
#pragma unroll
        for (int j = 0; j < 4; ++j) acc[i][j] = (f32x4){0.f, 0.f, 0.f, 0.f};

    stage_tile(0, 0);
    int cbuf = 0;
    const int NKT = I_DIM / BK;    // 16
#pragma unroll 2
    for (int t = 0; t < NKT; ++t) {
        if (t + 1 < NKT) {
            stage_tile(cbuf ^ 1, (t + 1) * BK);
            asm volatile("s_waitcnt vmcnt(8)" ::: "memory");
        } else {
            asm volatile("s_waitcnt vmcnt(0)" ::: "memory");
        }
        __builtin_amdgcn_s_barrier();
        COMPUTE_TILE();
        __builtin_amdgcn_s_barrier();
        cbuf ^= 1;
    }

    // epilogue: scatter rows to out via slot_tok
#pragma unroll
    for (int a = 0; a < 8; ++a) {
        const int mloc = wm * 128 + (a >> 2) * 64 + (a & 3) * 16 + lg * 4;
#pragma unroll
        for (int r = 0; r < 4; ++r) {
            const int tok = slot_tok[m0 + mloc + r];
            if (tok < 0) continue;
            float* orow = out + (size_t)tok * H_DIM + h0;
#pragma unroll
            for (int b = 0; b < 4; ++b) {
                const int hcol = wn * 64 + (b >> 1) * 32 + (b & 1) * 16 + lm;
                orow[hcol] = acc[a][b][r];
            }
        }
    }
}

extern "C" void kernel_launch(void* const* d_in, const int* in_sizes, int n_in,
                              void* d_out, int out_size, void* d_ws, size_t ws_size,
                              hipStream_t stream) {
    const float* x   = (const float*)d_in[0];
    const float* gw  = (const float*)d_in[1];
    const float* gup = (const float*)d_in[2];
    const float* dw  = (const float*)d_in[3];
    float* out = (float*)d_out;

    char* ws = (char*)d_ws;
    float* scale    = (float*)(ws + WS_SCALE);
    int*   counts   = (int*)(ws + WS_COUNTS);
    int*   offP     = (int*)(ws + WS_OFFP);
    int*   buckets  = (int*)(ws + WS_BUCKETS);
    int*   slot_tok = (int*)(ws + WS_SLOTTOK);
    short* xsg      = (short*)(ws + WS_XSG);
    short* act      = (short*)(ws + WS_ACT);
    short* wt       = (short*)(ws + WS_WT);    // shared: w1t then w2t

    hipMemsetAsync(counts, 0, E_NUM * sizeof(int), stream);
    router_kernel<<<T_TOK / 4, 256, 0, stream>>>(x, gw, scale, counts, buckets);
    offs_kernel<<<1, 64, 0, stream>>>(counts, offP);
    gather_kernel<<<MROWS, 256, 0, stream>>>(x, scale, counts, offP, buckets, xsg, slot_tok);

    // w1t = transpose(gate_up_weight) bf16, then GEMM1 (+SwiGLU)
    dim3 gt1(H_DIM / 64, TWO_I / 64, E_NUM);
    transpose_cvt_kernel<<<gt1, 256, 0, stream>>>(gup, wt, H_DIM, TWO_I);
    gemm1_8ph_kernel<<<8 * MT_MAX, 512, 0, stream>>>(xsg, wt, offP, act);

    // w2t = transpose(down_weight) bf16 (reuses region), then GEMM2 (+scatter)
    dim3 gt2(I_DIM / 64, H_DIM / 64, E_NUM);
    transpose_cvt_kernel<<<gt2, 256, 0, stream>>>(dw, wt, I_DIM, H_DIM);
    gemm2_8ph_kernel<<<8 * MT_MAX, 512, 0, stream>>>(act, wt, offP, slot_tok, out);
}